// Round 4
// baseline (263.449 us; speedup 1.0000x reference)
//
#include <hip/hip_runtime.h>
#include <hip/hip_fp16.h>

#define NXK 2048
#define NYK 2048
#define NC  (NXK - 1)   // 2047 cells per dim

typedef float f4 __attribute__((ext_vector_type(4)));

#define NTL(p) __builtin_nontemporal_load(p)

// ---------------- build: per-cell packed fp16 Hermite record (32 B) ----------------
// rec[cell] = 16 halfs: [f00,f01,f10,f11, gx00..gx11, gy00..gy11, gxy00..gxy11]
// gx = fx*dx, gy = fy*dy, gxy = fxy*dx*dy (premultiplied; raw fx ~ O(1e4) would
// lose fp16 accuracy, fx*dx ~ O(1) is safe).
// v4 (vectorized 2x4 block): each thread emits cells (i0..i0+1) x (c0..c0+3).
// 12 float4 NT loads (4 arrays x 3 node rows) + 12 scalar tail loads replace
// v3's 12 scalar loads PER CELL -> ~4x fewer mem-issue slots at identical bytes.
// Inputs NT-loaded (streamed once; biases L2/L3 residency toward the rec table,
// which the gather wants resident). rec stores stay temporal.
__global__ __launch_bounds__(256) void build_vec_kernel(
    const float* __restrict__ xk, const float* __restrict__ yk,
    const float* __restrict__ f,  const float* __restrict__ fx,
    const float* __restrict__ fy, const float* __restrict__ fxy,
    __half* __restrict__ rec)
{
    int c0 = (blockIdx.x * blockDim.x + threadIdx.x) * 4;  // first cell col
    int i0 = blockIdx.y * 2;                               // first cell row
    if (c0 >= NC) return;
    int  ncols = min(4, NC - c0);          // 4, or 3 for the last col group
    bool has2  = (i0 + 1) < NC;            // second cell row valid (uniform/block)
    bool xtra  = (c0 + 4) < NXK;           // node col c0+4 exists & is needed

    size_t r0 = (size_t)i0 * NYK + c0;     // node row i0,   cols c0..c0+3 (16B aligned)
    size_t r1 = r0 + NYK;                  // node row i0+1
    size_t r2 = r1 + NYK;                  // node row i0+2

    // ---- loads: rows 0..2 x {f,fx,fy,fxy}, float4 + scalar tail ----
    f4 vf[3], vx[3], vy[3], vw[3];
    float ef[3] = {0,0,0}, ex[3] = {0,0,0}, ey[3] = {0,0,0}, ew[3] = {0,0,0};

    vf[0] = NTL((const f4*)(f   + r0));
    vx[0] = NTL((const f4*)(fx  + r0));
    vy[0] = NTL((const f4*)(fy  + r0));
    vw[0] = NTL((const f4*)(fxy + r0));
    vf[1] = NTL((const f4*)(f   + r1));
    vx[1] = NTL((const f4*)(fx  + r1));
    vy[1] = NTL((const f4*)(fy  + r1));
    vw[1] = NTL((const f4*)(fxy + r1));
    if (has2) {
        vf[2] = NTL((const f4*)(f   + r2));
        vx[2] = NTL((const f4*)(fx  + r2));
        vy[2] = NTL((const f4*)(fy  + r2));
        vw[2] = NTL((const f4*)(fxy + r2));
    } else {
        vf[2] = vf[1]; vx[2] = vx[1]; vy[2] = vy[1]; vw[2] = vw[1];
    }
    if (xtra) {
        ef[0] = NTL(f + r0 + 4); ex[0] = NTL(fx + r0 + 4);
        ey[0] = NTL(fy + r0 + 4); ew[0] = NTL(fxy + r0 + 4);
        ef[1] = NTL(f + r1 + 4); ex[1] = NTL(fx + r1 + 4);
        ey[1] = NTL(fy + r1 + 4); ew[1] = NTL(fxy + r1 + 4);
        if (has2) {
            ef[2] = NTL(f + r2 + 4); ex[2] = NTL(fx + r2 + 4);
            ey[2] = NTL(fy + r2 + 4); ew[2] = NTL(fxy + r2 + 4);
        }
    }

    // knot spacings
    float dx0 = xk[i0 + 1] - xk[i0];
    float dx1 = has2 ? (xk[i0 + 2] - xk[i0 + 1]) : 0.0f;
    f4 ykv = *(const f4*)(yk + c0);                  // node cols c0..c0+3
    float yke = xtra ? yk[c0 + 4] : 0.0f;
    float dyc[4];
    dyc[0] = ykv[1] - ykv[0];
    dyc[1] = ykv[2] - ykv[1];
    dyc[2] = ykv[3] - ykv[2];
    dyc[3] = yke - ykv[3];                           // only used when ncols == 4

#pragma unroll
    for (int rr = 0; rr < 2; ++rr) {
        if (rr == 1 && !has2) break;
        float dxr = rr ? dx1 : dx0;
        size_t rowbase = (size_t)(i0 + rr) * NC;
#pragma unroll
        for (int cc = 0; cc < 4; ++cc) {
            if (cc >= ncols) break;
            // all vector indices compile-time after unroll (no scratch)
            float fA0 = vf[rr][cc],     fA1 = (cc < 3) ? vf[rr][cc + 1]     : ef[rr];
            float fB0 = vf[rr + 1][cc], fB1 = (cc < 3) ? vf[rr + 1][cc + 1] : ef[rr + 1];
            float xA0 = vx[rr][cc],     xA1 = (cc < 3) ? vx[rr][cc + 1]     : ex[rr];
            float xB0 = vx[rr + 1][cc], xB1 = (cc < 3) ? vx[rr + 1][cc + 1] : ex[rr + 1];
            float yA0 = vy[rr][cc],     yA1 = (cc < 3) ? vy[rr][cc + 1]     : ey[rr];
            float yB0 = vy[rr + 1][cc], yB1 = (cc < 3) ? vy[rr + 1][cc + 1] : ey[rr + 1];
            float wA0 = vw[rr][cc],     wA1 = (cc < 3) ? vw[rr][cc + 1]     : ew[rr];
            float wB0 = vw[rr + 1][cc], wB1 = (cc < 3) ? vw[rr + 1][cc + 1] : ew[rr + 1];

            float dyv = dyc[cc];
            float dxy = dxr * dyv;

            union { __half2 h2[8]; f4 v[2]; } r;
            r.h2[0] = __float22half2_rn(make_float2(fA0, fA1));
            r.h2[1] = __float22half2_rn(make_float2(fB0, fB1));
            r.h2[2] = __float22half2_rn(make_float2(xA0 * dxr, xA1 * dxr));
            r.h2[3] = __float22half2_rn(make_float2(xB0 * dxr, xB1 * dxr));
            r.h2[4] = __float22half2_rn(make_float2(yA0 * dyv, yA1 * dyv));
            r.h2[5] = __float22half2_rn(make_float2(yB0 * dyv, yB1 * dyv));
            r.h2[6] = __float22half2_rn(make_float2(wA0 * dxy, wA1 * dxy));
            r.h2[7] = __float22half2_rn(make_float2(wB0 * dxy, wB1 * dxy));

            f4* outp = reinterpret_cast<f4*>(rec + (rowbase + (c0 + cc)) * 16);
            outp[0] = r.v[0];
            outp[1] = r.v[1];
        }
    }
}

// ---------------- gather: 2 queries per thread (best measured config; FROZEN) ----
// locate(): floorf initial guess + searchsorted-exact correction loops.
// The correction loops are REQUIRED for correctness: interpax's A_CUBIC has
// u3(t) = -t^2(1+t) (== -2 at t=1), so the reference interpolant is
// DISCONTINUOUS at knots; cell selection must match searchsorted bit-exactly.
__device__ __forceinline__ int locate(float v, const float* __restrict__ k, int n) {
    int i = (int)floorf(v * (float)(n - 1));
    i = min(max(i, 0), n - 2);
    while (i < n - 2 && v >= k[i + 1]) ++i;
    while (i > 0 && v < k[i]) --i;
    return i;
}

struct RecU { union { float4 v[2]; __half2 h2[8]; }; };

__device__ __forceinline__ float eval_cell(float tx, float ty, const RecU& r) {
    // t-powers through interpax's A_CUBIC (note A[3,3] = -1)
    float u0 = 1.0f + tx * tx * (2.0f * tx - 3.0f);
    float u1 = tx * tx * (3.0f - 2.0f * tx);
    float u2 = tx * (1.0f + tx * (tx - 2.0f));
    float u3 = -tx * tx * (1.0f + tx);

    float v0 = 1.0f + ty * ty * (2.0f * ty - 3.0f);
    float v1 = ty * ty * (3.0f - 2.0f * ty);
    float v2 = ty * (1.0f + ty * (ty - 2.0f));
    float v3 = -ty * ty * (1.0f + ty);

    float2 a, b;
    a = __half22float2(r.h2[0]); b = __half22float2(r.h2[1]);
    float sf   = u0 * a.x + u2 * a.y + u1 * b.x + u3 * b.y;
    a = __half22float2(r.h2[2]); b = __half22float2(r.h2[3]);
    float sgx  = u0 * a.x + u2 * a.y + u1 * b.x + u3 * b.y;
    a = __half22float2(r.h2[4]); b = __half22float2(r.h2[5]);
    float sgy  = u0 * a.x + u2 * a.y + u1 * b.x + u3 * b.y;
    a = __half22float2(r.h2[6]); b = __half22float2(r.h2[7]);
    float sgxy = u0 * a.x + u2 * a.y + u1 * b.x + u3 * b.y;

    return v0 * sf + v1 * sgx + v2 * sgy + v3 * sgxy;
}

__global__ __launch_bounds__(256) void gather2_kernel(
    const float* __restrict__ xq, const float* __restrict__ yq,
    const float* __restrict__ xk, const float* __restrict__ yk,
    const __half* __restrict__ rec,
    float* __restrict__ out, int nq, int half)
{
    int t = blockIdx.x * blockDim.x + threadIdx.x;
    if (t >= half) return;
    int q0 = t;
    int q1t = t + half;
    bool has1 = q1t < nq;
    int q1 = has1 ? q1t : q0;

    // streaming data: non-temporal so the record table keeps L2/L3 residency
    float xv0 = __builtin_nontemporal_load(xq + q0);
    float yv0 = __builtin_nontemporal_load(yq + q0);
    float xv1 = __builtin_nontemporal_load(xq + q1);
    float yv1 = __builtin_nontemporal_load(yq + q1);

    int il0 = locate(xv0, xk, NXK);
    int jl0 = locate(yv0, yk, NYK);
    int il1 = locate(xv1, xk, NXK);
    int jl1 = locate(yv1, yk, NYK);

    // issue all 4 random 16B record loads before consuming any (2x MLP/thread)
    const float4* rp0 = reinterpret_cast<const float4*>(rec) + ((size_t)il0 * NC + jl0) * 2;
    const float4* rp1 = reinterpret_cast<const float4*>(rec) + ((size_t)il1 * NC + jl1) * 2;
    RecU r0, r1;
    r0.v[0] = rp0[0];
    r0.v[1] = rp0[1];
    r1.v[0] = rp1[0];
    r1.v[1] = rp1[1];

    float x00 = xk[il0], dx0 = xk[il0 + 1] - x00;
    float tx0 = (xv0 - x00) * ((dx0 == 0.0f) ? 0.0f : 1.0f / dx0);
    float y00 = yk[jl0], dy0 = yk[jl0 + 1] - y00;
    float ty0 = (yv0 - y00) * ((dy0 == 0.0f) ? 0.0f : 1.0f / dy0);

    float x01 = xk[il1], dx1 = xk[il1 + 1] - x01;
    float tx1 = (xv1 - x01) * ((dx1 == 0.0f) ? 0.0f : 1.0f / dx1);
    float y01 = yk[jl1], dy1 = yk[jl1 + 1] - y01;
    float ty1 = (yv1 - y01) * ((dy1 == 0.0f) ? 0.0f : 1.0f / dy1);

    float o0 = eval_cell(tx0, ty0, r0);
    __builtin_nontemporal_store(o0, out + q0);
    if (has1) {
        float o1 = eval_cell(tx1, ty1, r1);
        __builtin_nontemporal_store(o1, out + q1);
    }
}

// ---------------- fallback (direct gather, no workspace) ----------------
__global__ __launch_bounds__(256) void interp2d_direct(
    const float* __restrict__ xq, const float* __restrict__ yq,
    const float* __restrict__ xk, const float* __restrict__ yk,
    const float* __restrict__ f,  const float* __restrict__ fx,
    const float* __restrict__ fy, const float* __restrict__ fxy,
    float* __restrict__ out, int nq)
{
    int q = blockIdx.x * blockDim.x + threadIdx.x;
    if (q >= nq) return;

    float xv = xq[q];
    float yv = yq[q];

    int il = locate(xv, xk, NXK);
    int jl = locate(yv, yk, NYK);

    float x0 = xk[il], x1 = xk[il + 1];
    float dx = x1 - x0;
    float tx = (xv - x0) * ((dx == 0.0f) ? 0.0f : 1.0f / dx);
    float y0 = yk[jl], y1 = yk[jl + 1];
    float dy = y1 - y0;
    float ty = (yv - y0) * ((dy == 0.0f) ? 0.0f : 1.0f / dy);

    float u0 = 1.0f + tx * tx * (2.0f * tx - 3.0f);
    float u1 = tx * tx * (3.0f - 2.0f * tx);
    float u2 = tx * (1.0f + tx * (tx - 2.0f));
    float u3 = -tx * tx * (1.0f + tx);
    float v0 = 1.0f + ty * ty * (2.0f * ty - 3.0f);
    float v1 = ty * ty * (3.0f - 2.0f * ty);
    float v2 = ty * (1.0f + ty * (ty - 2.0f));
    float v3 = -ty * ty * (1.0f + ty);

    long base = (long)il * NYK + jl;
    const float* p = f + base;
    float sf   = u0 * p[0] + u2 * p[1] + u1 * p[NYK] + u3 * p[NYK + 1];
    p = fx + base;
    float sfx  = u0 * p[0] + u2 * p[1] + u1 * p[NYK] + u3 * p[NYK + 1];
    p = fy + base;
    float sfy  = u0 * p[0] + u2 * p[1] + u1 * p[NYK] + u3 * p[NYK + 1];
    p = fxy + base;
    float sfxy = u0 * p[0] + u2 * p[1] + u1 * p[NYK] + u3 * p[NYK + 1];

    out[q] = v0 * sf + v1 * (sfx * dx) + v2 * (sfy * dy) + v3 * (sfxy * (dx * dy));
}

extern "C" void kernel_launch(void* const* d_in, const int* in_sizes, int n_in,
                              void* d_out, int out_size, void* d_ws, size_t ws_size,
                              hipStream_t stream) {
    const float* xq  = (const float*)d_in[0];
    const float* yq  = (const float*)d_in[1];
    const float* xk  = (const float*)d_in[2];
    const float* yk  = (const float*)d_in[3];
    const float* f   = (const float*)d_in[4];
    const float* fx  = (const float*)d_in[5];
    const float* fy  = (const float*)d_in[6];
    const float* fxy = (const float*)d_in[7];
    float* out = (float*)d_out;

    int nq = in_sizes[0];
    const size_t rec_bytes = (size_t)NC * NC * 16 * sizeof(__half);  // ~134 MB

    if (ws_size >= rec_bytes) {
        __half* rec = (__half*)d_ws;
        int colgroups = (NC + 3) / 4;                     // 512
        int rowpairs  = (NC + 1) / 2;                     // 1024
        dim3 bgrid((colgroups + 255) / 256, rowpairs);    // (2, 1024)
        build_vec_kernel<<<bgrid, 256, 0, stream>>>(xk, yk, f, fx, fy, fxy, rec);
        int half = (nq + 1) / 2;
        int grid = (half + 255) / 256;
        gather2_kernel<<<grid, 256, 0, stream>>>(xq, yq, xk, yk, rec, out, nq, half);
    } else {
        int grid = (nq + 255) / 256;
        interp2d_direct<<<grid, 256, 0, stream>>>(xq, yq, xk, yk, f, fx, fy, fxy, out, nq);
    }
}

// Round 5
// 242.813 us; speedup vs baseline: 1.0850x; 1.0850x over previous
//
#include <hip/hip_runtime.h>
#include <hip/hip_fp16.h>

#define NXK 2048
#define NYK 2048
#define NC  (NXK - 1)   // 2047 cells per dim

#define NTL(p) __builtin_nontemporal_load(p)

// ---------------- build: per-cell packed fp16 Hermite record (32 B) ----------------
// rec[cell] = 16 halfs: [f00,f01,f10,f11, gx00..gx11, gy00..gy11, gxy00..gxy11]
// gx = fx*dx, gy = fy*dy, gxy = fxy*dx*dy  (premultiplied at build time;
// raw fx ~ O(1e4) would lose fp16 accuracy, fx*dx ~ O(1) is safe).
// FINAL: vertical-pair build (round-3 best, 243.6 us total). Each thread emits
// cells (2i,j) and (2i+1,j), reading node rows 2i..2i+2 once. v4's 2x4
// vectorized variant REGRESSED (+20 us): its f4 stores had 128 B lane stride
// (one line touch per lane per store -> defeated write combining) and 4x fewer
// threads hid NT-read latency worse. Scalar loads + record-contiguous stores
// (lane stride 32 B) is the measured optimum for this kernel.
__global__ __launch_bounds__(256) void build_pair_kernel(
    const float* __restrict__ xk, const float* __restrict__ yk,
    const float* __restrict__ f,  const float* __restrict__ fx,
    const float* __restrict__ fy, const float* __restrict__ fxy,
    __half* __restrict__ rec)
{
    int j  = blockIdx.x * blockDim.x + threadIdx.x;   // cell col
    int i0 = blockIdx.y * 2;                          // first cell row of pair
    if (j >= NC) return;
    bool has2 = (i0 + 1) < NC;                        // second cell row valid

    size_t r0 = (size_t)i0 * NYK + j;
    size_t r1 = r0 + NYK;
    size_t r2 = r1 + NYK;

    float dx0 = xk[i0 + 1] - xk[i0];
    float dx1 = has2 ? (xk[i0 + 2] - xk[i0 + 1]) : 0.0f;
    float dy  = yk[j + 1] - yk[j];

    // node rows i0, i0+1 (always), i0+2 (if has2); cols j, j+1; 4 arrays
    float f00 = NTL(f + r0),  f01 = NTL(f + r0 + 1);
    float f10 = NTL(f + r1),  f11 = NTL(f + r1 + 1);
    float x00 = NTL(fx + r0), x01 = NTL(fx + r0 + 1);
    float x10 = NTL(fx + r1), x11 = NTL(fx + r1 + 1);
    float y00 = NTL(fy + r0), y01 = NTL(fy + r0 + 1);
    float y10 = NTL(fy + r1), y11 = NTL(fy + r1 + 1);
    float w00 = NTL(fxy + r0), w01 = NTL(fxy + r0 + 1);
    float w10 = NTL(fxy + r1), w11 = NTL(fxy + r1 + 1);

    float f20 = 0.f, f21 = 0.f, x20 = 0.f, x21 = 0.f;
    float y20 = 0.f, y21 = 0.f, w20 = 0.f, w21 = 0.f;
    if (has2) {
        f20 = NTL(f + r2);  f21 = NTL(f + r2 + 1);
        x20 = NTL(fx + r2); x21 = NTL(fx + r2 + 1);
        y20 = NTL(fy + r2); y21 = NTL(fy + r2 + 1);
        w20 = NTL(fxy + r2); w21 = NTL(fxy + r2 + 1);
    }

    union { __half h[16]; float4 v[2]; } rA;
    float dxy0 = dx0 * dy;
    rA.h[0]  = __float2half(f00);        rA.h[1]  = __float2half(f01);
    rA.h[2]  = __float2half(f10);        rA.h[3]  = __float2half(f11);
    rA.h[4]  = __float2half(x00 * dx0);  rA.h[5]  = __float2half(x01 * dx0);
    rA.h[6]  = __float2half(x10 * dx0);  rA.h[7]  = __float2half(x11 * dx0);
    rA.h[8]  = __float2half(y00 * dy);   rA.h[9]  = __float2half(y01 * dy);
    rA.h[10] = __float2half(y10 * dy);   rA.h[11] = __float2half(y11 * dy);
    rA.h[12] = __float2half(w00 * dxy0); rA.h[13] = __float2half(w01 * dxy0);
    rA.h[14] = __float2half(w10 * dxy0); rA.h[15] = __float2half(w11 * dxy0);

    float4* outA = reinterpret_cast<float4*>(rec + ((size_t)i0 * NC + j) * 16);
    outA[0] = rA.v[0];
    outA[1] = rA.v[1];

    if (has2) {
        union { __half h[16]; float4 v[2]; } rB;
        float dxy1 = dx1 * dy;
        rB.h[0]  = __float2half(f10);        rB.h[1]  = __float2half(f11);
        rB.h[2]  = __float2half(f20);        rB.h[3]  = __float2half(f21);
        rB.h[4]  = __float2half(x10 * dx1);  rB.h[5]  = __float2half(x11 * dx1);
        rB.h[6]  = __float2half(x20 * dx1);  rB.h[7]  = __float2half(x21 * dx1);
        rB.h[8]  = __float2half(y10 * dy);   rB.h[9]  = __float2half(y11 * dy);
        rB.h[10] = __float2half(y20 * dy);   rB.h[11] = __float2half(y21 * dy);
        rB.h[12] = __float2half(w10 * dxy1); rB.h[13] = __float2half(w11 * dxy1);
        rB.h[14] = __float2half(w20 * dxy1); rB.h[15] = __float2half(w21 * dxy1);

        float4* outB = reinterpret_cast<float4*>(rec + ((size_t)(i0 + 1) * NC + j) * 16);
        outB[0] = rB.v[0];
        outB[1] = rB.v[1];
    }
}

// ---------------- gather: 2 queries per thread (best measured config; FROZEN) ----
// locate(): floorf initial guess + searchsorted-exact correction loops.
// The correction loops are REQUIRED for correctness: interpax's A_CUBIC has
// u3(t) = -t^2(1+t) (== -2 at t=1), so the reference interpolant is
// DISCONTINUOUS at knots; cell selection must match searchsorted bit-exactly.
__device__ __forceinline__ int locate(float v, const float* __restrict__ k, int n) {
    int i = (int)floorf(v * (float)(n - 1));
    i = min(max(i, 0), n - 2);
    while (i < n - 2 && v >= k[i + 1]) ++i;
    while (i > 0 && v < k[i]) --i;
    return i;
}

struct RecU { union { float4 v[2]; __half2 h2[8]; }; };

__device__ __forceinline__ float eval_cell(float tx, float ty, const RecU& r) {
    // t-powers through interpax's A_CUBIC (note A[3,3] = -1)
    float u0 = 1.0f + tx * tx * (2.0f * tx - 3.0f);
    float u1 = tx * tx * (3.0f - 2.0f * tx);
    float u2 = tx * (1.0f + tx * (tx - 2.0f));
    float u3 = -tx * tx * (1.0f + tx);

    float v0 = 1.0f + ty * ty * (2.0f * ty - 3.0f);
    float v1 = ty * ty * (3.0f - 2.0f * ty);
    float v2 = ty * (1.0f + ty * (ty - 2.0f));
    float v3 = -ty * ty * (1.0f + ty);

    float2 a, b;
    a = __half22float2(r.h2[0]); b = __half22float2(r.h2[1]);
    float sf   = u0 * a.x + u2 * a.y + u1 * b.x + u3 * b.y;
    a = __half22float2(r.h2[2]); b = __half22float2(r.h2[3]);
    float sgx  = u0 * a.x + u2 * a.y + u1 * b.x + u3 * b.y;
    a = __half22float2(r.h2[4]); b = __half22float2(r.h2[5]);
    float sgy  = u0 * a.x + u2 * a.y + u1 * b.x + u3 * b.y;
    a = __half22float2(r.h2[6]); b = __half22float2(r.h2[7]);
    float sgxy = u0 * a.x + u2 * a.y + u1 * b.x + u3 * b.y;

    return v0 * sf + v1 * sgx + v2 * sgy + v3 * sgxy;
}

__global__ __launch_bounds__(256) void gather2_kernel(
    const float* __restrict__ xq, const float* __restrict__ yq,
    const float* __restrict__ xk, const float* __restrict__ yk,
    const __half* __restrict__ rec,
    float* __restrict__ out, int nq, int half)
{
    int t = blockIdx.x * blockDim.x + threadIdx.x;
    if (t >= half) return;
    int q0 = t;
    int q1t = t + half;
    bool has1 = q1t < nq;
    int q1 = has1 ? q1t : q0;

    // streaming data: non-temporal so the record table keeps L2/L3 residency
    float xv0 = __builtin_nontemporal_load(xq + q0);
    float yv0 = __builtin_nontemporal_load(yq + q0);
    float xv1 = __builtin_nontemporal_load(xq + q1);
    float yv1 = __builtin_nontemporal_load(yq + q1);

    int il0 = locate(xv0, xk, NXK);
    int jl0 = locate(yv0, yk, NYK);
    int il1 = locate(xv1, xk, NXK);
    int jl1 = locate(yv1, yk, NYK);

    // issue all 4 random 16B record loads before consuming any (2x MLP/thread)
    const float4* rp0 = reinterpret_cast<const float4*>(rec) + ((size_t)il0 * NC + jl0) * 2;
    const float4* rp1 = reinterpret_cast<const float4*>(rec) + ((size_t)il1 * NC + jl1) * 2;
    RecU r0, r1;
    r0.v[0] = rp0[0];
    r0.v[1] = rp0[1];
    r1.v[0] = rp1[0];
    r1.v[1] = rp1[1];

    float x00 = xk[il0], dx0 = xk[il0 + 1] - x00;
    float tx0 = (xv0 - x00) * ((dx0 == 0.0f) ? 0.0f : 1.0f / dx0);
    float y00 = yk[jl0], dy0 = yk[jl0 + 1] - y00;
    float ty0 = (yv0 - y00) * ((dy0 == 0.0f) ? 0.0f : 1.0f / dy0);

    float x01 = xk[il1], dx1 = xk[il1 + 1] - x01;
    float tx1 = (xv1 - x01) * ((dx1 == 0.0f) ? 0.0f : 1.0f / dx1);
    float y01 = yk[jl1], dy1 = yk[jl1 + 1] - y01;
    float ty1 = (yv1 - y01) * ((dy1 == 0.0f) ? 0.0f : 1.0f / dy1);

    float o0 = eval_cell(tx0, ty0, r0);
    __builtin_nontemporal_store(o0, out + q0);
    if (has1) {
        float o1 = eval_cell(tx1, ty1, r1);
        __builtin_nontemporal_store(o1, out + q1);
    }
}

// ---------------- fallback (direct gather, no workspace) ----------------
__global__ __launch_bounds__(256) void interp2d_direct(
    const float* __restrict__ xq, const float* __restrict__ yq,
    const float* __restrict__ xk, const float* __restrict__ yk,
    const float* __restrict__ f,  const float* __restrict__ fx,
    const float* __restrict__ fy, const float* __restrict__ fxy,
    float* __restrict__ out, int nq)
{
    int q = blockIdx.x * blockDim.x + threadIdx.x;
    if (q >= nq) return;

    float xv = xq[q];
    float yv = yq[q];

    int il = locate(xv, xk, NXK);
    int jl = locate(yv, yk, NYK);

    float x0 = xk[il], x1 = xk[il + 1];
    float dx = x1 - x0;
    float tx = (xv - x0) * ((dx == 0.0f) ? 0.0f : 1.0f / dx);
    float y0 = yk[jl], y1 = yk[jl + 1];
    float dy = y1 - y0;
    float ty = (yv - y0) * ((dy == 0.0f) ? 0.0f : 1.0f / dy);

    float u0 = 1.0f + tx * tx * (2.0f * tx - 3.0f);
    float u1 = tx * tx * (3.0f - 2.0f * tx);
    float u2 = tx * (1.0f + tx * (tx - 2.0f));
    float u3 = -tx * tx * (1.0f + tx);
    float v0 = 1.0f + ty * ty * (2.0f * ty - 3.0f);
    float v1 = ty * ty * (3.0f - 2.0f * ty);
    float v2 = ty * (1.0f + ty * (ty - 2.0f));
    float v3 = -ty * ty * (1.0f + ty);

    long base = (long)il * NYK + jl;
    const float* p = f + base;
    float sf   = u0 * p[0] + u2 * p[1] + u1 * p[NYK] + u3 * p[NYK + 1];
    p = fx + base;
    float sfx  = u0 * p[0] + u2 * p[1] + u1 * p[NYK] + u3 * p[NYK + 1];
    p = fy + base;
    float sfy  = u0 * p[0] + u2 * p[1] + u1 * p[NYK] + u3 * p[NYK + 1];
    p = fxy + base;
    float sfxy = u0 * p[0] + u2 * p[1] + u1 * p[NYK] + u3 * p[NYK + 1];

    out[q] = v0 * sf + v1 * (sfx * dx) + v2 * (sfy * dy) + v3 * (sfxy * (dx * dy));
}

extern "C" void kernel_launch(void* const* d_in, const int* in_sizes, int n_in,
                              void* d_out, int out_size, void* d_ws, size_t ws_size,
                              hipStream_t stream) {
    const float* xq  = (const float*)d_in[0];
    const float* yq  = (const float*)d_in[1];
    const float* xk  = (const float*)d_in[2];
    const float* yk  = (const float*)d_in[3];
    const float* f   = (const float*)d_in[4];
    const float* fx  = (const float*)d_in[5];
    const float* fy  = (const float*)d_in[6];
    const float* fxy = (const float*)d_in[7];
    float* out = (float*)d_out;

    int nq = in_sizes[0];
    const size_t rec_bytes = (size_t)NC * NC * 16 * sizeof(__half);  // ~134 MB

    if (ws_size >= rec_bytes) {
        __half* rec = (__half*)d_ws;
        int npairs = (NC + 1) / 2;                        // 1024 row pairs
        dim3 bgrid((NC + 255) / 256, npairs);             // (8, 1024)
        build_pair_kernel<<<bgrid, 256, 0, stream>>>(xk, yk, f, fx, fy, fxy, rec);
        int half = (nq + 1) / 2;
        int grid = (half + 255) / 256;
        gather2_kernel<<<grid, 256, 0, stream>>>(xq, yq, xk, yk, rec, out, nq, half);
    } else {
        int grid = (nq + 255) / 256;
        interp2d_direct<<<grid, 255 + 1, 0, stream>>>(xq, yq, xk, yk, f, fx, fy, fxy, out, nq);
    }
}